// Round 4
// baseline (552.417 us; speedup 1.0000x reference)
//
#include <hip/hip_runtime.h>
#include <math.h>

// GCN 2-layer forward on MI355X — round 9.
//  Changes vs round 8:
//   * agg1+gemm2 fused (k_aggemm): block owns 64 nodes; waves aggregate
//     16 nodes each (round-8 agg1 body) writing h1 rows straight into the
//     LDS As tile; barrier; round-8 gemm2 MFMA phase consumes the tile.
//     Kills the h1 global round-trip and one dispatch.
//   * weight prep folded into the bhist dispatch as fat-role blocks;
//     gemm1 rides in thirds with bscan/part/bsort.
//  Dispatches: memset, d1(bhist∪prep), d2(bscan∪g1a), d3(part∪g1b),
//              d4(bsort∪g1c), aggemm, agg2  = 6 kernels.

typedef unsigned int uint;
typedef unsigned short ushort_t;
using short8  = __attribute__((ext_vector_type(8))) short;
using float4v = __attribute__((ext_vector_type(4))) float;

__device__ __forceinline__ ushort_t f2bf(float f) {
    uint u = __float_as_uint(f);
    u += 0x7FFFu + ((u >> 16) & 1u);   // RNE
    return (ushort_t)(u >> 16);
}
__device__ __forceinline__ float2 unpack2(uint v) {
    return make_float2(__uint_as_float(v << 16), __uint_as_float(v & 0xFFFF0000u));
}
__device__ __forceinline__ uint pack2(float a, float b) {
    return (uint)f2bf(a) | ((uint)f2bf(b) << 16);
}
__device__ __forceinline__ void acc8(float* acc, uint4 v) {
    float2 a0 = unpack2(v.x), a1 = unpack2(v.y), a2 = unpack2(v.z), a3 = unpack2(v.w);
    acc[0] += a0.x; acc[1] += a0.y; acc[2] += a1.x; acc[3] += a1.y;
    acc[4] += a2.x; acc[5] += a2.y; acc[6] += a3.x; acc[7] += a3.y;
}
__device__ __forceinline__ void acc8s(float* acc, uint4 v, float d) {
    float2 a0 = unpack2(v.x), a1 = unpack2(v.y), a2 = unpack2(v.z), a3 = unpack2(v.w);
    acc[0] = fmaf(d, a0.x, acc[0]); acc[1] = fmaf(d, a0.y, acc[1]);
    acc[2] = fmaf(d, a1.x, acc[2]); acc[3] = fmaf(d, a1.y, acc[3]);
    acc[4] = fmaf(d, a2.x, acc[4]); acc[5] = fmaf(d, a2.y, acc[5]);
    acc[6] = fmaf(d, a3.x, acc[6]); acc[7] = fmaf(d, a3.y, acc[7]);
}

// ---- GEMM1 block body (RAW: no dinv) ------------------------------------
__device__ __forceinline__ void gemm1_block(int gb, const float* __restrict__ x,
                                            const ushort_t* __restrict__ W1t,
                                            ushort_t* __restrict__ h, int n) {
    __shared__ ushort_t As[64][72];
    __shared__ ushort_t Bs[128][72];
    const int tid  = threadIdx.x;
    const int w    = tid >> 6, lane = tid & 63;
    const int quad = lane >> 4, l16 = lane & 15;
    const int row0 = gb * 64;

    float4v acc[8];
#pragma unroll
    for (int i = 0; i < 8; i++) acc[i] = (float4v)0.f;

    const int ar  = tid >> 2;
    const int akq = (tid & 3) * 16;
    const int br  = tid >> 1;
    const int bkq = (tid & 1) * 32;
    const int agrow = row0 + ar;
    const float* xp0 = &x[(size_t)agrow * 512];
    const ushort_t* wp0 = &W1t[(size_t)br * 512];

    for (int kb = 0; kb < 512; kb += 64) {
#pragma unroll
        for (int j = 0; j < 4; j++) {
            float4 v = make_float4(0.f, 0.f, 0.f, 0.f);
            if (agrow < n) v = *(const float4*)(xp0 + kb + akq + j * 4);
            ushort4 b;
            b.x = f2bf(v.x); b.y = f2bf(v.y); b.z = f2bf(v.z); b.w = f2bf(v.w);
            *(ushort4*)&As[ar][akq + j * 4] = b;
        }
#pragma unroll
        for (int j = 0; j < 8; j++) {
            *(ushort4*)&Bs[br][bkq + j * 4] = *(const ushort4*)(wp0 + kb + bkq + j * 4);
        }
        __syncthreads();
#pragma unroll
        for (int ks = 0; ks < 64; ks += 32) {
            short8 a = *(const short8*)&As[w * 16 + l16][ks + quad * 8];
#pragma unroll
            for (int ct = 0; ct < 8; ct++) {
                short8 b = *(const short8*)&Bs[ct * 16 + l16][ks + quad * 8];
                acc[ct] = __builtin_amdgcn_mfma_f32_16x16x32_bf16(a, b, acc[ct], 0, 0, 0);
            }
        }
        __syncthreads();
    }
#pragma unroll
    for (int r = 0; r < 4; r++) {
        int grow = row0 + w * 16 + quad * 4 + r;
        if (grow >= n) continue;
#pragma unroll
        for (int ct = 0; ct < 8; ct++) {
            int col = ct * 16 + l16;
            h[(size_t)grow * 128 + col] = f2bf(acc[ct][r]);
        }
    }
}

// ---- D1: bhist (blocks < nblkA) ∪ weight prep ---------------------------
__global__ __launch_bounds__(256) void k_d1(const int* __restrict__ dst,
                                            int* __restrict__ bcnt, int e, int nb, int nblkA,
                                            const float* __restrict__ W1,
                                            const float* __restrict__ W2,
                                            ushort_t* __restrict__ W1t,
                                            ushort_t* __restrict__ W2t) {
    if ((int)blockIdx.x >= nblkA) {
        int idx = ((int)blockIdx.x - nblkA) * 256 + threadIdx.x;   // 71936 threads
        if (idx < 65536) {
            int nn = idx >> 9, k = idx & 511;
            W1t[idx] = f2bf(W1[(size_t)k * 128 + nn]);
        } else if (idx < 71680) {
            int j = idx - 65536;
            int c = j >> 7, k = j & 127;
            W2t[j] = (c < 40) ? f2bf(W2[(size_t)k * 40 + c]) : (ushort_t)0;
        }
        return;
    }
    __shared__ int sh[800];
    for (int t = threadIdx.x; t < nb; t += 256) sh[t] = 0;
    __syncthreads();
    int ibase = blockIdx.x * 2560 + threadIdx.x;
#pragma unroll
    for (int j = 0; j < 10; j++) {
        int i = ibase + j * 256;
        if (i < e) atomicAdd(&sh[dst[i] >> 7], 1);
    }
    __syncthreads();
    for (int t = threadIdx.x; t < nb; t += 256) {
        int c = sh[t];
        if (c) atomicAdd(&bcnt[t], c);
    }
}

// ---- D2: bscan (block 0) ∪ gemm1 chunk ----------------------------------
__global__ __launch_bounds__(256) void k_d2(const int* __restrict__ bcnt, int* __restrict__ bbase,
                                            int* __restrict__ bcur, int* __restrict__ row_ptr,
                                            int nb, int n, int e,
                                            const float* __restrict__ x,
                                            const ushort_t* __restrict__ W1t,
                                            ushort_t* __restrict__ h, int goff) {
    if (blockIdx.x > 0) {
        gemm1_block((int)blockIdx.x - 1 + goff, x, W1t, h, n);
        return;
    }
    __shared__ int sd[256];
    int t = threadIdx.x;
    int base = t * 4;
    int v[4];
#pragma unroll
    for (int j = 0; j < 4; j++) v[j] = (base + j < nb) ? bcnt[base + j] : 0;
    int s0 = v[0], s1 = s0 + v[1], s2 = s1 + v[2], s3 = s2 + v[3];
    sd[t] = s3;
    __syncthreads();
    for (int d = 1; d < 256; d <<= 1) {
        int xv = (t >= d) ? sd[t - d] : 0;
        __syncthreads();
        sd[t] += xv;
        __syncthreads();
    }
    int excl = sd[t] - s3;
    int pre0 = excl, pre1 = excl + s0, pre2 = excl + s1, pre3 = excl + s2;
    if (base + 0 < nb) { bbase[base + 0] = pre0; bcur[base + 0] = pre0; }
    if (base + 1 < nb) { bbase[base + 1] = pre1; bcur[base + 1] = pre1; }
    if (base + 2 < nb) { bbase[base + 2] = pre2; bcur[base + 2] = pre2; }
    if (base + 3 < nb) { bbase[base + 3] = pre3; bcur[base + 3] = pre3; }
    if (t == 255) bbase[nb] = excl + s3;   // == e
    if (t == 0) row_ptr[n] = e;
}

// ---- D3: part (blocks < nblkA) ∪ gemm1 chunk ----------------------------
__global__ __launch_bounds__(256) void k_d3(const int* __restrict__ src, const int* __restrict__ dst,
                                            int* __restrict__ bcur, uint* __restrict__ pbuf,
                                            int e, int nb, int nblkA,
                                            const float* __restrict__ x,
                                            const ushort_t* __restrict__ W1t,
                                            ushort_t* __restrict__ h, int n, int goff) {
    if ((int)blockIdx.x >= nblkA) {
        gemm1_block((int)blockIdx.x - nblkA + goff, x, W1t, h, n);
        return;
    }
    __shared__ int sh[800];
    __shared__ int base_l[800];
    for (int t = threadIdx.x; t < nb; t += 256) sh[t] = 0;
    __syncthreads();
    uint pk[10]; int bk[10]; int lp[10];
    int ibase = blockIdx.x * 2560 + threadIdx.x;
#pragma unroll
    for (int j = 0; j < 10; j++) {
        int i = ibase + j * 256;
        bk[j] = -1;
        if (i < e) {
            int s = src[i], d = dst[i];
            int b = d >> 7;
            bk[j] = b;
            pk[j] = ((uint)(d & 127) << 25) | (uint)s;
            lp[j] = atomicAdd(&sh[b], 1);
        }
    }
    __syncthreads();
    for (int t = threadIdx.x; t < nb; t += 256) {
        int c = sh[t];
        base_l[t] = c ? atomicAdd(&bcur[t], c) : 0;
    }
    __syncthreads();
#pragma unroll
    for (int j = 0; j < 10; j++) {
        if (bk[j] >= 0) pbuf[base_l[bk[j]] + lp[j]] = pk[j];
    }
}

// ---- D4: bsort (blocks < NB) ∪ gemm1 chunk ------------------------------
__global__ __launch_bounds__(256) void k_d4(const uint* __restrict__ pbuf,
                                            const int* __restrict__ bbase,
                                            float* __restrict__ dinv,
                                            int* __restrict__ row_ptr,
                                            int* __restrict__ es_src, int n, int nb,
                                            const float* __restrict__ x,
                                            const ushort_t* __restrict__ W1t,
                                            ushort_t* __restrict__ h, int goff) {
    if ((int)blockIdx.x >= nb) {
        gemm1_block((int)blockIdx.x - nb + goff, x, W1t, h, n);
        return;
    }
    __shared__ int cl[128];
    __shared__ int cur[128];
    const int b = blockIdx.x;
    const int tid = threadIdx.x;
    const int ebeg = bbase[b], eend = bbase[b + 1];
    const int m = eend - ebeg;
    if (tid < 128) cl[tid] = 0;
    __syncthreads();
    for (int i = tid; i < m; i += 256) {
        uint p = pbuf[ebeg + i];
        atomicAdd(&cl[p >> 25], 1);
    }
    __syncthreads();
    int own = (tid < 128) ? cl[tid] : 0;
    for (int d = 1; d < 128; d <<= 1) {
        int v = 0;
        if (tid < 128 && tid >= d) v = cl[tid - d];
        __syncthreads();
        if (tid < 128 && tid >= d) cl[tid] += v;
        __syncthreads();
    }
    if (tid < 128) {
        int excl = cl[tid] - own;
        int node = b * 128 + tid;
        if (node < n) {
            dinv[node] = rsqrtf((float)(own + 1));   // deg incl. self-loop
            row_ptr[node] = ebeg + excl;
        }
        cur[tid] = excl;
    }
    __syncthreads();
    for (int i = tid; i < m; i += 256) {
        uint p = pbuf[ebeg + i];
        int dl = (int)(p >> 25);
        int pos = atomicAdd(&cur[dl], 1);
        es_src[ebeg + pos] = (int)(p & 0x1FFFFFFu);
    }
}

// ---- fused agg1 + gemm2 --------------------------------------------------
// Block owns 64 nodes. Phase A: wave w aggregates nodes row0+w*16+i
// (i=0..15) with the round-8 agg1 body (4 groups x dwordx4, dinv[src] fma),
// writing h1 rows straight into LDS As[64][136]. Phase B: round-8 gemm2
// MFMA from the tile; writes g = bf16(dinv*(h1@W2)) padded to 64 cols.
__global__ __launch_bounds__(256) void k_aggemm(const uint* __restrict__ h,
                                                const int* __restrict__ row_ptr,
                                                const int* __restrict__ es_src,
                                                const float* __restrict__ dinv,
                                                const float* __restrict__ b1,
                                                const ushort_t* __restrict__ W2t,
                                                ushort_t* __restrict__ g, int n) {
    __shared__ ushort_t As[64][136];
    __shared__ ushort_t Bs[48][136];
    const int tid  = threadIdx.x;
    const int w    = tid >> 6, lane = tid & 63;
    const int row0 = blockIdx.x * 64;
    const int g4   = lane >> 4;     // group 0..3
    const int l16  = lane & 15;     // cols [l16*8, l16*8+8)

    // stage Bs (W2t)
    for (int i = tid; i < 768; i += 256) {
        int row = i >> 4, q = i & 15;
        *(uint4*)&Bs[row][q * 8] = *(const uint4*)&W2t[(size_t)row * 128 + q * 8];
    }

    // Phase A: aggregation, 16 nodes per wave
    for (int i = 0; i < 16; i++) {
        const int r    = w * 16 + i;
        const int node = row0 + r;
        if (node >= n) {
            if (g4 == 0) *(uint4*)&As[r][l16 * 8] = make_uint4(0, 0, 0, 0);
            continue;
        }
        const int k0 = row_ptr[node], k1 = row_ptr[node + 1];
        const float di = dinv[node];
        uint4 sv = *(const uint4*)&h[(size_t)node * 64 + l16 * 4];   // self, early

        float acc[8];
#pragma unroll
        for (int j = 0; j < 8; j++) acc[j] = 0.f;

        int k = k0 + g4;
        for (; k + 4 < k1; k += 8) {        // 8 edges per wave iteration
            int s0 = es_src[k];
            int s1 = es_src[k + 4];
            float d0 = dinv[s0], d1 = dinv[s1];
            uint4 v0 = *(const uint4*)&h[(size_t)s0 * 64 + l16 * 4];
            uint4 v1 = *(const uint4*)&h[(size_t)s1 * 64 + l16 * 4];
            acc8s(acc, v0, d0);
            acc8s(acc, v1, d1);
        }
        for (; k < k1; k += 4) {            // tail: 4 edges per iteration
            int s0 = es_src[k];
            float d0 = dinv[s0];
            uint4 v0 = *(const uint4*)&h[(size_t)s0 * 64 + l16 * 4];
            acc8s(acc, v0, d0);
        }
#pragma unroll
        for (int j = 0; j < 8; j++) {
            acc[j] += __shfl_xor(acc[j], 16);
            acc[j] += __shfl_xor(acc[j], 32);
        }
        acc8s(acc, sv, di);                 // self term, once

        float4 ba = *(const float4*)&b1[l16 * 8];
        float4 bb = *(const float4*)&b1[l16 * 8 + 4];
        float rr[8];
        rr[0] = di * acc[0] + ba.x; rr[1] = di * acc[1] + ba.y;
        rr[2] = di * acc[2] + ba.z; rr[3] = di * acc[3] + ba.w;
        rr[4] = di * acc[4] + bb.x; rr[5] = di * acc[5] + bb.y;
        rr[6] = di * acc[6] + bb.z; rr[7] = di * acc[7] + bb.w;
#pragma unroll
        for (int j = 0; j < 8; j++) rr[j] = rr[j] > 0.f ? rr[j] : 0.f;

        if (g4 == 0) {
            uint4 o;
            o.x = pack2(rr[0], rr[1]); o.y = pack2(rr[2], rr[3]);
            o.z = pack2(rr[4], rr[5]); o.w = pack2(rr[6], rr[7]);
            *(uint4*)&As[r][l16 * 8] = o;
        }
    }
    __syncthreads();

    // Phase B: MFMA h1-tile @ W2
    const int quad = lane >> 4;
    float4v acc[3];
#pragma unroll
    for (int i = 0; i < 3; i++) acc[i] = (float4v)0.f;
#pragma unroll
    for (int ks = 0; ks < 128; ks += 32) {
        short8 a = *(const short8*)&As[w * 16 + l16][ks + quad * 8];
#pragma unroll
        for (int ct = 0; ct < 3; ct++) {
            short8 b = *(const short8*)&Bs[ct * 16 + l16][ks + quad * 8];
            acc[ct] = __builtin_amdgcn_mfma_f32_16x16x32_bf16(a, b, acc[ct], 0, 0, 0);
        }
    }
#pragma unroll
    for (int r = 0; r < 4; r++) {
        int grow = row0 + w * 16 + quad * 4 + r;
        if (grow >= n) continue;
        float di = dinv[grow];
#pragma unroll
        for (int ct = 0; ct < 3; ct++) {
            int col = ct * 16 + l16;
            g[(size_t)grow * 64 + col] = f2bf(di * acc[ct][r]);
        }
        g[(size_t)grow * 64 + 48 + l16] = (ushort_t)0;   // zero pad cols 48..63
    }
}

// ---- agg2 + bias + log_softmax fused ------------------------------------
__global__ __launch_bounds__(256) void k_agg2(const uint* __restrict__ g,
                                              const int* __restrict__ row_ptr,
                                              const int* __restrict__ es_src,
                                              const float* __restrict__ dinv,
                                              const float* __restrict__ b2,
                                              float* __restrict__ out1,
                                              float* __restrict__ out2, int n) {
    const int tid  = threadIdx.x;
    const int node = blockIdx.x * 4 + (tid >> 6);
    if (node >= n) return;
    const int lane = tid & 63;
    const int g8   = lane >> 3;     // group 0..7
    const int l8   = lane & 7;      // cols [l8*8, l8*8+8)
    const int k0 = row_ptr[node], k1 = row_ptr[node + 1];

    uint4 sv = *(const uint4*)&g[(size_t)node * 32 + l8 * 4];   // self, early

    float acc[8];
#pragma unroll
    for (int i = 0; i < 8; i++) acc[i] = 0.f;

    int k = k0 + g8;
    for (; k + 8 < k1; k += 16) {       // 16 edges per wave iteration
        int s0 = es_src[k];
        int s1 = es_src[k + 8];
        uint4 v0 = *(const uint4*)&g[(size_t)s0 * 32 + l8 * 4];
        uint4 v1 = *(const uint4*)&g[(size_t)s1 * 32 + l8 * 4];
        acc8(acc, v0);
        acc8(acc, v1);
    }
    for (; k < k1; k += 8) {            // tail: 8 edges per iteration
        int s0 = es_src[k];
        uint4 v0 = *(const uint4*)&g[(size_t)s0 * 32 + l8 * 4];
        acc8(acc, v0);
    }

    // combine the 8 groups
#pragma unroll
    for (int i = 0; i < 8; i++) {
        acc[i] += __shfl_xor(acc[i], 8);
        acc[i] += __shfl_xor(acc[i], 16);
        acc[i] += __shfl_xor(acc[i], 32);
    }
    acc8(acc, sv);                      // self, once

    const float di = dinv[node];
    float v[8];
    if (l8 < 5) {
        float4 ba = *(const float4*)&b2[l8 * 8];
        float4 bb = *(const float4*)&b2[l8 * 8 + 4];
        v[0] = di * acc[0] + ba.x; v[1] = di * acc[1] + ba.y;
        v[2] = di * acc[2] + ba.z; v[3] = di * acc[3] + ba.w;
        v[4] = di * acc[4] + bb.x; v[5] = di * acc[5] + bb.y;
        v[6] = di * acc[6] + bb.z; v[7] = di * acc[7] + bb.w;
    } else {
#pragma unroll
        for (int i = 0; i < 8; i++) v[i] = 0.f;
    }

    // log-softmax over the 40 real cols (lanes l8<5 hold 8 each)
    float m = -1e30f;
    if (l8 < 5) {
#pragma unroll
        for (int i = 0; i < 8; i++) m = fmaxf(m, v[i]);
    }
#pragma unroll
    for (int d = 1; d < 8; d <<= 1) m = fmaxf(m, __shfl_xor(m, d));
    float s = 0.f;
    if (l8 < 5) {
#pragma unroll
        for (int i = 0; i < 8; i++) s += expf(v[i] - m);
    }
#pragma unroll
    for (int d = 1; d < 8; d <<= 1) s += __shfl_xor(s, d);
    float ls = logf(s) + m;

    if (l8 < 5) {
        if (g8 == 0) {
            *(float4*)&out1[(size_t)node * 40 + l8 * 8]     = make_float4(v[0], v[1], v[2], v[3]);
            *(float4*)&out1[(size_t)node * 40 + l8 * 8 + 4] = make_float4(v[4], v[5], v[6], v[7]);
        } else if (g8 == 1) {
            *(float4*)&out2[(size_t)node * 40 + l8 * 8] =
                make_float4(v[0] - ls, v[1] - ls, v[2] - ls, v[3] - ls);
            *(float4*)&out2[(size_t)node * 40 + l8 * 8 + 4] =
                make_float4(v[4] - ls, v[5] - ls, v[6] - ls, v[7] - ls);
        }
    }
}

static inline size_t align4(size_t v) { return (v + 3) & ~(size_t)3; }

extern "C" void kernel_launch(void* const* d_in, const int* in_sizes, int n_in,
                              void* d_out, int out_size, void* d_ws, size_t ws_size,
                              hipStream_t stream) {
    const float* x  = (const float*)d_in[0];
    const int*   ei = (const int*)d_in[1];
    const float* W1 = (const float*)d_in[2];
    const float* b1 = (const float*)d_in[3];
    const float* W2 = (const float*)d_in[4];
    const float* b2 = (const float*)d_in[5];

    const int n = in_sizes[0] / 512;
    const int e = in_sizes[1] / 2;
    const int* src = ei;
    const int* dst = ei + e;
    const int NB = (n + 127) >> 7;           // buckets of 128 nodes (<=800)

    char* p = (char*)d_ws;
    int*      bcnt    = (int*)p;        p += align4(NB) * 4;
    int*      bbase   = (int*)p;        p += align4(NB + 1) * 4;
    int*      bcur    = (int*)p;        p += align4(NB) * 4;
    int*      row_ptr = (int*)p;        p += align4(n + 1) * 4;
    float*    dinv    = (float*)p;      p += align4(n) * 4;
    uint*     pbuf    = (uint*)p;       p += align4(e) * 4;
    int*      es_src  = (int*)p;        p += align4(e) * 4;
    ushort_t* W1t     = (ushort_t*)p;   p += (size_t)128 * 512 * 2;
    ushort_t* W2t     = (ushort_t*)p;   p += (size_t)48 * 128 * 2;
    ushort_t* h       = (ushort_t*)p;   p += (size_t)n * 128 * 2;   // h' raw bf16
    ushort_t* g       = (ushort_t*)p;   p += (size_t)n * 64 * 2;    // [n,64] bf16 pad
    float*    out1    = (float*)d_out;
    float*    out2    = out1 + (size_t)n * 40;

    const int B = 256;
    const int nblkA = (e + 2559) / 2560;
    const int NG = (n + 63) / 64;           // gemm1 blocks total
    const int c  = (NG + 2) / 3;            // chunk size (thirds)
    const int c2 = NG - 2 * c;              // last chunk

    hipMemsetAsync(bcnt, 0, (size_t)NB * 4, stream);

    // CSR build overlapped with weight prep + gemm1 thirds
    k_d1<<<nblkA + 281, B, 0, stream>>>(dst, bcnt, e, NB, nblkA, W1, W2, W1t, W2t);
    k_d2<<<1 + c, B, 0, stream>>>(bcnt, bbase, bcur, row_ptr, NB, n, e, x, W1t, h, 0);
    k_d3<<<nblkA + c, B, 0, stream>>>(src, dst, bcur, pbuf, e, NB, nblkA, x, W1t, h, n, c);
    k_d4<<<NB + c2, B, 0, stream>>>(pbuf, bbase, dinv, row_ptr, es_src, n, NB, x, W1t, h, 2 * c);

    // fused agg1 + gemm2
    k_aggemm<<<NG, B, 0, stream>>>((const uint*)h, row_ptr, es_src, dinv, b1, W2t, g, n);

    // agg2 + log_softmax
    k_agg2<<<(n + 3) / 4, B, 0, stream>>>((const uint*)g, row_ptr, es_src, dinv, b2, out1, out2, n);
}

// Round 5
// 536.674 us; speedup vs baseline: 1.0293x; 1.0293x over previous
//
#include <hip/hip_runtime.h>
#include <math.h>

// GCN 2-layer forward on MI355X — round 10.
//  Round-9 fusion REVERTED (LDS+barrier capped gather occupancy at 37%).
//  Back to round-8 structure; aggregation gathers rebuilt for concurrency:
//   * indices staged coalesced (1 vmem per 32/64 edges) + dinv gathered
//     per-lane, broadcast to groups via __shfl (outside predication).
//   * 8-deep predicated unroll -> up to 8 row-loads in flight per group
//     (round 8 had 2), ~10x fewer index/address instructions per edge.
//  Dispatches: memset, d1(bhist∪prep), d2(bscan∪g1a), d3(part∪g1b),
//              d4(bsort∪g1c), agg1, gemm2, agg2.

typedef unsigned int uint;
typedef unsigned short ushort_t;
using short8  = __attribute__((ext_vector_type(8))) short;
using float4v = __attribute__((ext_vector_type(4))) float;

__device__ __forceinline__ ushort_t f2bf(float f) {
    uint u = __float_as_uint(f);
    u += 0x7FFFu + ((u >> 16) & 1u);   // RNE
    return (ushort_t)(u >> 16);
}
__device__ __forceinline__ float2 unpack2(uint v) {
    return make_float2(__uint_as_float(v << 16), __uint_as_float(v & 0xFFFF0000u));
}
__device__ __forceinline__ uint pack2(float a, float b) {
    return (uint)f2bf(a) | ((uint)f2bf(b) << 16);
}
__device__ __forceinline__ void acc8(float* acc, uint4 v) {
    float2 a0 = unpack2(v.x), a1 = unpack2(v.y), a2 = unpack2(v.z), a3 = unpack2(v.w);
    acc[0] += a0.x; acc[1] += a0.y; acc[2] += a1.x; acc[3] += a1.y;
    acc[4] += a2.x; acc[5] += a2.y; acc[6] += a3.x; acc[7] += a3.y;
}
__device__ __forceinline__ void acc8s(float* acc, uint4 v, float d) {
    float2 a0 = unpack2(v.x), a1 = unpack2(v.y), a2 = unpack2(v.z), a3 = unpack2(v.w);
    acc[0] = fmaf(d, a0.x, acc[0]); acc[1] = fmaf(d, a0.y, acc[1]);
    acc[2] = fmaf(d, a1.x, acc[2]); acc[3] = fmaf(d, a1.y, acc[3]);
    acc[4] = fmaf(d, a2.x, acc[4]); acc[5] = fmaf(d, a2.y, acc[5]);
    acc[6] = fmaf(d, a3.x, acc[6]); acc[7] = fmaf(d, a3.y, acc[7]);
}

// ---- GEMM1 block body (RAW: no dinv) ------------------------------------
__device__ __forceinline__ void gemm1_block(int gb, const float* __restrict__ x,
                                            const ushort_t* __restrict__ W1t,
                                            ushort_t* __restrict__ h, int n) {
    __shared__ ushort_t As[64][72];
    __shared__ ushort_t Bs[128][72];
    const int tid  = threadIdx.x;
    const int w    = tid >> 6, lane = tid & 63;
    const int quad = lane >> 4, l16 = lane & 15;
    const int row0 = gb * 64;

    float4v acc[8];
#pragma unroll
    for (int i = 0; i < 8; i++) acc[i] = (float4v)0.f;

    const int ar  = tid >> 2;
    const int akq = (tid & 3) * 16;
    const int br  = tid >> 1;
    const int bkq = (tid & 1) * 32;
    const int agrow = row0 + ar;
    const float* xp0 = &x[(size_t)agrow * 512];
    const ushort_t* wp0 = &W1t[(size_t)br * 512];

    for (int kb = 0; kb < 512; kb += 64) {
#pragma unroll
        for (int j = 0; j < 4; j++) {
            float4 v = make_float4(0.f, 0.f, 0.f, 0.f);
            if (agrow < n) v = *(const float4*)(xp0 + kb + akq + j * 4);
            ushort4 b;
            b.x = f2bf(v.x); b.y = f2bf(v.y); b.z = f2bf(v.z); b.w = f2bf(v.w);
            *(ushort4*)&As[ar][akq + j * 4] = b;
        }
#pragma unroll
        for (int j = 0; j < 8; j++) {
            *(ushort4*)&Bs[br][bkq + j * 4] = *(const ushort4*)(wp0 + kb + bkq + j * 4);
        }
        __syncthreads();
#pragma unroll
        for (int ks = 0; ks < 64; ks += 32) {
            short8 a = *(const short8*)&As[w * 16 + l16][ks + quad * 8];
#pragma unroll
            for (int ct = 0; ct < 8; ct++) {
                short8 b = *(const short8*)&Bs[ct * 16 + l16][ks + quad * 8];
                acc[ct] = __builtin_amdgcn_mfma_f32_16x16x32_bf16(a, b, acc[ct], 0, 0, 0);
            }
        }
        __syncthreads();
    }
#pragma unroll
    for (int r = 0; r < 4; r++) {
        int grow = row0 + w * 16 + quad * 4 + r;
        if (grow >= n) continue;
#pragma unroll
        for (int ct = 0; ct < 8; ct++) {
            int col = ct * 16 + l16;
            h[(size_t)grow * 128 + col] = f2bf(acc[ct][r]);
        }
    }
}

// ---- D1: bhist (blocks < nblkA) ∪ weight prep ---------------------------
__global__ __launch_bounds__(256) void k_d1(const int* __restrict__ dst,
                                            int* __restrict__ bcnt, int e, int nb, int nblkA,
                                            const float* __restrict__ W1,
                                            const float* __restrict__ W2,
                                            ushort_t* __restrict__ W1t,
                                            ushort_t* __restrict__ W2t) {
    if ((int)blockIdx.x >= nblkA) {
        int idx = ((int)blockIdx.x - nblkA) * 256 + threadIdx.x;   // 71680 threads
        if (idx < 65536) {
            int nn = idx >> 9, k = idx & 511;
            W1t[idx] = f2bf(W1[(size_t)k * 128 + nn]);
        } else if (idx < 71680) {
            int j = idx - 65536;
            int c = j >> 7, k = j & 127;
            W2t[j] = (c < 40) ? f2bf(W2[(size_t)k * 40 + c]) : (ushort_t)0;
        }
        return;
    }
    __shared__ int sh[800];
    for (int t = threadIdx.x; t < nb; t += 256) sh[t] = 0;
    __syncthreads();
    int ibase = blockIdx.x * 2560 + threadIdx.x;
#pragma unroll
    for (int j = 0; j < 10; j++) {
        int i = ibase + j * 256;
        if (i < e) atomicAdd(&sh[dst[i] >> 7], 1);
    }
    __syncthreads();
    for (int t = threadIdx.x; t < nb; t += 256) {
        int c = sh[t];
        if (c) atomicAdd(&bcnt[t], c);
    }
}

// ---- D2: bscan (block 0) ∪ gemm1 chunk ----------------------------------
__global__ __launch_bounds__(256) void k_d2(const int* __restrict__ bcnt, int* __restrict__ bbase,
                                            int* __restrict__ bcur, int* __restrict__ row_ptr,
                                            int nb, int n, int e,
                                            const float* __restrict__ x,
                                            const ushort_t* __restrict__ W1t,
                                            ushort_t* __restrict__ h, int goff) {
    if (blockIdx.x > 0) {
        gemm1_block((int)blockIdx.x - 1 + goff, x, W1t, h, n);
        return;
    }
    __shared__ int sd[256];
    int t = threadIdx.x;
    int base = t * 4;
    int v[4];
#pragma unroll
    for (int j = 0; j < 4; j++) v[j] = (base + j < nb) ? bcnt[base + j] : 0;
    int s0 = v[0], s1 = s0 + v[1], s2 = s1 + v[2], s3 = s2 + v[3];
    sd[t] = s3;
    __syncthreads();
    for (int d = 1; d < 256; d <<= 1) {
        int xv = (t >= d) ? sd[t - d] : 0;
        __syncthreads();
        sd[t] += xv;
        __syncthreads();
    }
    int excl = sd[t] - s3;
    int pre0 = excl, pre1 = excl + s0, pre2 = excl + s1, pre3 = excl + s2;
    if (base + 0 < nb) { bbase[base + 0] = pre0; bcur[base + 0] = pre0; }
    if (base + 1 < nb) { bbase[base + 1] = pre1; bcur[base + 1] = pre1; }
    if (base + 2 < nb) { bbase[base + 2] = pre2; bcur[base + 2] = pre2; }
    if (base + 3 < nb) { bbase[base + 3] = pre3; bcur[base + 3] = pre3; }
    if (t == 255) bbase[nb] = excl + s3;   // == e
    if (t == 0) row_ptr[n] = e;
}

// ---- D3: part (blocks < nblkA) ∪ gemm1 chunk ----------------------------
__global__ __launch_bounds__(256) void k_d3(const int* __restrict__ src, const int* __restrict__ dst,
                                            int* __restrict__ bcur, uint* __restrict__ pbuf,
                                            int e, int nb, int nblkA,
                                            const float* __restrict__ x,
                                            const ushort_t* __restrict__ W1t,
                                            ushort_t* __restrict__ h, int n, int goff) {
    if ((int)blockIdx.x >= nblkA) {
        gemm1_block((int)blockIdx.x - nblkA + goff, x, W1t, h, n);
        return;
    }
    __shared__ int sh[800];
    __shared__ int base_l[800];
    for (int t = threadIdx.x; t < nb; t += 256) sh[t] = 0;
    __syncthreads();
    uint pk[10]; int bk[10]; int lp[10];
    int ibase = blockIdx.x * 2560 + threadIdx.x;
#pragma unroll
    for (int j = 0; j < 10; j++) {
        int i = ibase + j * 256;
        bk[j] = -1;
        if (i < e) {
            int s = src[i], d = dst[i];
            int b = d >> 7;
            bk[j] = b;
            pk[j] = ((uint)(d & 127) << 25) | (uint)s;
            lp[j] = atomicAdd(&sh[b], 1);
        }
    }
    __syncthreads();
    for (int t = threadIdx.x; t < nb; t += 256) {
        int c = sh[t];
        base_l[t] = c ? atomicAdd(&bcur[t], c) : 0;
    }
    __syncthreads();
#pragma unroll
    for (int j = 0; j < 10; j++) {
        if (bk[j] >= 0) pbuf[base_l[bk[j]] + lp[j]] = pk[j];
    }
}

// ---- D4: bsort (blocks < NB) ∪ gemm1 chunk ------------------------------
__global__ __launch_bounds__(256) void k_d4(const uint* __restrict__ pbuf,
                                            const int* __restrict__ bbase,
                                            float* __restrict__ dinv,
                                            int* __restrict__ row_ptr,
                                            int* __restrict__ es_src, int n, int nb,
                                            const float* __restrict__ x,
                                            const ushort_t* __restrict__ W1t,
                                            ushort_t* __restrict__ h, int goff) {
    if ((int)blockIdx.x >= nb) {
        gemm1_block((int)blockIdx.x - nb + goff, x, W1t, h, n);
        return;
    }
    __shared__ int cl[128];
    __shared__ int cur[128];
    const int b = blockIdx.x;
    const int tid = threadIdx.x;
    const int ebeg = bbase[b], eend = bbase[b + 1];
    const int m = eend - ebeg;
    if (tid < 128) cl[tid] = 0;
    __syncthreads();
    for (int i = tid; i < m; i += 256) {
        uint p = pbuf[ebeg + i];
        atomicAdd(&cl[p >> 25], 1);
    }
    __syncthreads();
    int own = (tid < 128) ? cl[tid] : 0;
    for (int d = 1; d < 128; d <<= 1) {
        int v = 0;
        if (tid < 128 && tid >= d) v = cl[tid - d];
        __syncthreads();
        if (tid < 128 && tid >= d) cl[tid] += v;
        __syncthreads();
    }
    if (tid < 128) {
        int excl = cl[tid] - own;
        int node = b * 128 + tid;
        if (node < n) {
            dinv[node] = rsqrtf((float)(own + 1));   // deg incl. self-loop
            row_ptr[node] = ebeg + excl;
        }
        cur[tid] = excl;
    }
    __syncthreads();
    for (int i = tid; i < m; i += 256) {
        uint p = pbuf[ebeg + i];
        int dl = (int)(p >> 25);
        int pos = atomicAdd(&cur[dl], 1);
        es_src[ebeg + pos] = (int)(p & 0x1FFFFFFu);
    }
}

// ---- agg1: h1 = bf16(relu(dinv[i]*(dinv[i]h[i]+Σ dinv[s]h[s]) + b1)) ----
// one wave per node; 4 groups of 16 lanes. Indices staged coalesced
// (lanes 0-31 load 32 edges + their dinv in one shot), broadcast by shfl;
// each group issues up to 8 row-loads (dwordx4) back-to-back.
__global__ __launch_bounds__(256) void k_agg1(const uint* __restrict__ h,
                                              const int* __restrict__ row_ptr,
                                              const int* __restrict__ es_src,
                                              const float* __restrict__ dinv,
                                              const float* __restrict__ b1,
                                              uint* __restrict__ h1, int n) {
    const int tid  = threadIdx.x;
    const int node = blockIdx.x * 4 + (tid >> 6);
    if (node >= n) return;
    const int lane = tid & 63;
    const int g4   = lane >> 4;     // group 0..3
    const int l16  = lane & 15;     // cols [l16*8, l16*8+8)
    const int k0 = row_ptr[node], k1 = row_ptr[node + 1];
    const float di = dinv[node];

    uint4 sv = *(const uint4*)&h[(size_t)node * 64 + l16 * 4];   // self, early

    float acc[8];
#pragma unroll
    for (int i = 0; i < 8; i++) acc[i] = 0.f;

    int k = k0;
    while (k < k1) {
        int rem = k1 - k;
        int cnt = rem < 32 ? rem : 32;
        int idx = 0; float dv = 0.f;
        if (lane < cnt) {
            idx = es_src[k + lane];
            dv  = dinv[idx];
        }
#pragma unroll
        for (int t = 0; t < 8; t++) {
            int j = g4 + 4 * t;                 // group g4 takes edges j
            int   s = __shfl(idx, j);           // all lanes execute shfl
            float d = __shfl(dv, j);
            if (j < cnt) {
                uint4 v = *(const uint4*)&h[(size_t)s * 64 + l16 * 4];
                acc8s(acc, v, d);
            }
        }
        k += cnt;
    }

    // combine the 4 groups
#pragma unroll
    for (int i = 0; i < 8; i++) {
        acc[i] += __shfl_xor(acc[i], 16);
        acc[i] += __shfl_xor(acc[i], 32);
    }
    acc8s(acc, sv, di);                 // self term, once

    float4 ba = *(const float4*)&b1[l16 * 8];
    float4 bb = *(const float4*)&b1[l16 * 8 + 4];
    float r[8];
    r[0] = di * acc[0] + ba.x; r[1] = di * acc[1] + ba.y;
    r[2] = di * acc[2] + ba.z; r[3] = di * acc[3] + ba.w;
    r[4] = di * acc[4] + bb.x; r[5] = di * acc[5] + bb.y;
    r[6] = di * acc[6] + bb.z; r[7] = di * acc[7] + bb.w;
#pragma unroll
    for (int i = 0; i < 8; i++) r[i] = r[i] > 0.f ? r[i] : 0.f;

    if (g4 == 0) {
        uint4 o;
        o.x = pack2(r[0], r[1]); o.y = pack2(r[2], r[3]);
        o.z = pack2(r[4], r[5]); o.w = pack2(r[6], r[7]);
        *(uint4*)&h1[(size_t)node * 64 + l16 * 4] = o;
    }
}

// ---- GEMM2 (MFMA bf16): g[i] = bf16(dinv[i] * (h1 @ W2)[i]), [n,64] pad -
__global__ __launch_bounds__(256) void k_gemm2(const ushort_t* __restrict__ h1,
                                               const ushort_t* __restrict__ W2t,
                                               const float* __restrict__ dinv,
                                               ushort_t* __restrict__ g, int n) {
    __shared__ ushort_t As[64][136];
    __shared__ ushort_t Bs[48][136];
    const int tid  = threadIdx.x;
    const int w    = tid >> 6, lane = tid & 63;
    const int quad = lane >> 4, l16 = lane & 15;
    const int row0 = blockIdx.x * 64;

    {
        int ar = tid >> 2;
        int ak = (tid & 3) * 32;
        int grow = row0 + ar;
#pragma unroll
        for (int j = 0; j < 4; j++) {
            uint4 v = make_uint4(0, 0, 0, 0);
            if (grow < n) v = *(const uint4*)&h1[(size_t)grow * 128 + ak + j * 8];
            *(uint4*)&As[ar][ak + j * 8] = v;
        }
    }
    for (int i = tid; i < 768; i += 256) {
        int row = i >> 4, q = i & 15;
        *(uint4*)&Bs[row][q * 8] = *(const uint4*)&W2t[(size_t)row * 128 + q * 8];
    }
    __syncthreads();

    float4v acc[3];
#pragma unroll
    for (int i = 0; i < 3; i++) acc[i] = (float4v)0.f;
#pragma unroll
    for (int ks = 0; ks < 128; ks += 32) {
        short8 a = *(const short8*)&As[w * 16 + l16][ks + quad * 8];
#pragma unroll
        for (int ct = 0; ct < 3; ct++) {
            short8 b = *(const short8*)&Bs[ct * 16 + l16][ks + quad * 8];
            acc[ct] = __builtin_amdgcn_mfma_f32_16x16x32_bf16(a, b, acc[ct], 0, 0, 0);
        }
    }
#pragma unroll
    for (int r = 0; r < 4; r++) {
        int grow = row0 + w * 16 + quad * 4 + r;
        if (grow >= n) continue;
        float di = dinv[grow];
#pragma unroll
        for (int ct = 0; ct < 3; ct++) {
            int col = ct * 16 + l16;
            g[(size_t)grow * 64 + col] = f2bf(di * acc[ct][r]);
        }
        g[(size_t)grow * 64 + 48 + l16] = (ushort_t)0;   // zero pad cols 48..63
    }
}

// ---- agg2 + bias + log_softmax fused ------------------------------------
// one wave per node; 8 groups of 8 lanes. Indices staged coalesced
// (all 64 lanes load 64 edges in one shot), broadcast by shfl;
// each group issues up to 8 row-loads (dwordx4) back-to-back.
__global__ __launch_bounds__(256) void k_agg2(const uint* __restrict__ g,
                                              const int* __restrict__ row_ptr,
                                              const int* __restrict__ es_src,
                                              const float* __restrict__ dinv,
                                              const float* __restrict__ b2,
                                              float* __restrict__ out1,
                                              float* __restrict__ out2, int n) {
    const int tid  = threadIdx.x;
    const int node = blockIdx.x * 4 + (tid >> 6);
    if (node >= n) return;
    const int lane = tid & 63;
    const int g8   = lane >> 3;     // group 0..7
    const int l8   = lane & 7;      // cols [l8*8, l8*8+8)
    const int k0 = row_ptr[node], k1 = row_ptr[node + 1];

    uint4 sv = *(const uint4*)&g[(size_t)node * 32 + l8 * 4];   // self, early

    float acc[8];
#pragma unroll
    for (int i = 0; i < 8; i++) acc[i] = 0.f;

    int k = k0;
    while (k < k1) {
        int rem = k1 - k;
        int cnt = rem < 64 ? rem : 64;
        int idx = 0;
        if (lane < cnt) idx = es_src[k + lane];
#pragma unroll
        for (int t = 0; t < 8; t++) {
            int j = g8 + 8 * t;                 // group g8 takes edges j
            int s = __shfl(idx, j);             // all lanes execute shfl
            if (j < cnt) {
                uint4 v = *(const uint4*)&g[(size_t)s * 32 + l8 * 4];
                acc8(acc, v);
            }
        }
        k += cnt;
    }

    // combine the 8 groups
#pragma unroll
    for (int i = 0; i < 8; i++) {
        acc[i] += __shfl_xor(acc[i], 8);
        acc[i] += __shfl_xor(acc[i], 16);
        acc[i] += __shfl_xor(acc[i], 32);
    }
    acc8(acc, sv);                      // self, once

    const float di = dinv[node];
    float v[8];
    if (l8 < 5) {
        float4 ba = *(const float4*)&b2[l8 * 8];
        float4 bb = *(const float4*)&b2[l8 * 8 + 4];
        v[0] = di * acc[0] + ba.x; v[1] = di * acc[1] + ba.y;
        v[2] = di * acc[2] + ba.z; v[3] = di * acc[3] + ba.w;
        v[4] = di * acc[4] + bb.x; v[5] = di * acc[5] + bb.y;
        v[6] = di * acc[6] + bb.z; v[7] = di * acc[7] + bb.w;
    } else {
#pragma unroll
        for (int i = 0; i < 8; i++) v[i] = 0.f;
    }

    // log-softmax over the 40 real cols (lanes l8<5 hold 8 each)
    float m = -1e30f;
    if (l8 < 5) {
#pragma unroll
        for (int i = 0; i < 8; i++) m = fmaxf(m, v[i]);
    }
#pragma unroll
    for (int d = 1; d < 8; d <<= 1) m = fmaxf(m, __shfl_xor(m, d));
    float s = 0.f;
    if (l8 < 5) {
#pragma unroll
        for (int i = 0; i < 8; i++) s += expf(v[i] - m);
    }
#pragma unroll
    for (int d = 1; d < 8; d <<= 1) s += __shfl_xor(s, d);
    float ls = logf(s) + m;

    if (l8 < 5) {
        if (g8 == 0) {
            *(float4*)&out1[(size_t)node * 40 + l8 * 8]     = make_float4(v[0], v[1], v[2], v[3]);
            *(float4*)&out1[(size_t)node * 40 + l8 * 8 + 4] = make_float4(v[4], v[5], v[6], v[7]);
        } else if (g8 == 1) {
            *(float4*)&out2[(size_t)node * 40 + l8 * 8] =
                make_float4(v[0] - ls, v[1] - ls, v[2] - ls, v[3] - ls);
            *(float4*)&out2[(size_t)node * 40 + l8 * 8 + 4] =
                make_float4(v[4] - ls, v[5] - ls, v[6] - ls, v[7] - ls);
        }
    }
}

static inline size_t align4(size_t v) { return (v + 3) & ~(size_t)3; }

extern "C" void kernel_launch(void* const* d_in, const int* in_sizes, int n_in,
                              void* d_out, int out_size, void* d_ws, size_t ws_size,
                              hipStream_t stream) {
    const float* x  = (const float*)d_in[0];
    const int*   ei = (const int*)d_in[1];
    const float* W1 = (const float*)d_in[2];
    const float* b1 = (const float*)d_in[3];
    const float* W2 = (const float*)d_in[4];
    const float* b2 = (const float*)d_in[5];

    const int n = in_sizes[0] / 512;
    const int e = in_sizes[1] / 2;
    const int* src = ei;
    const int* dst = ei + e;
    const int NB = (n + 127) >> 7;           // buckets of 128 nodes (<=800)

    char* p = (char*)d_ws;
    int*      bcnt    = (int*)p;        p += align4(NB) * 4;
    int*      bbase   = (int*)p;        p += align4(NB + 1) * 4;
    int*      bcur    = (int*)p;        p += align4(NB) * 4;
    int*      row_ptr = (int*)p;        p += align4(n + 1) * 4;
    float*    dinv    = (float*)p;      p += align4(n) * 4;
    uint*     pbuf    = (uint*)p;       p += align4(e) * 4;
    int*      es_src  = (int*)p;        p += align4(e) * 4;
    ushort_t* W1t     = (ushort_t*)p;   p += (size_t)128 * 512 * 2;
    ushort_t* W2t     = (ushort_t*)p;   p += (size_t)48 * 128 * 2;
    ushort_t* h       = (ushort_t*)p;   p += (size_t)n * 128 * 2;   // h' raw bf16; g overlays
    ushort_t* h1      = (ushort_t*)p;   p += (size_t)n * 128 * 2;   // bf16
    ushort_t* g       = h;                                          // [n,64] bf16, 128 B rows
    float*    out1    = (float*)d_out;
    float*    out2    = out1 + (size_t)n * 40;

    const int B = 256;
    const int nblkA = (e + 2559) / 2560;
    const int NG = (n + 63) / 64;           // gemm1 blocks total
    const int c  = (NG + 2) / 3;            // chunk size (thirds)
    const int c2 = NG - 2 * c;              // last chunk

    hipMemsetAsync(bcnt, 0, (size_t)NB * 4, stream);

    // CSR build overlapped with weight prep + gemm1 thirds
    k_d1<<<nblkA + 280, B, 0, stream>>>(dst, bcnt, e, NB, nblkA, W1, W2, W1t, W2t);
    k_d2<<<1 + c, B, 0, stream>>>(bcnt, bbase, bcur, row_ptr, NB, n, e, x, W1t, h, 0);
    k_d3<<<nblkA + c, B, 0, stream>>>(src, dst, bcur, pbuf, e, NB, nblkA, x, W1t, h, n, c);
    k_d4<<<NB + c2, B, 0, stream>>>(pbuf, bbase, dinv, row_ptr, es_src, n, NB, x, W1t, h, 2 * c);

    // layer 1 aggregation (dinv[src] applied at gather)
    k_agg1<<<(n + 3) / 4, B, 0, stream>>>((const uint*)h, row_ptr, es_src, dinv, b1, (uint*)h1, n);

    // layer 2
    k_gemm2<<<(n + 63) / 64, B, 0, stream>>>(h1, W2t, dinv, g, n);
    k_agg2<<<(n + 3) / 4, B, 0, stream>>>((const uint*)g, row_ptr, es_src, dinv, b2, out1, out2, n);
}